// Round 1
// baseline (2735.015 us; speedup 1.0000x reference)
//
#include <hip/hip_runtime.h>

// Problem constants (shapes fixed by the reference)
#define S_TOK 8
#define D_DIM 128
#define H_HEADS 4
#define DH 32
#define NODE_F (S_TOK * D_DIM)          // 1024 floats per node
#define WSTRIDE (6*128*128 + 6*128)     // per-relation prepped-weight block (floats)

struct RelW { const float *Win, *bin, *Wb, *bb, *Wo, *bo; };

// ---------------------------------------------------------------------------
// Weight prep: per relation, build TRANSPOSED (Wt[k][o]) projection matrices:
//  mat 0: Qt  = scale * Wq        (applied to x_dst)   bias0 = scale*bq
//  mat 1: Kt  = Wk                (applied to x_dst)   bias1 = bk
//  mat 2: Vt  = Wv                (applied to x_dst)   bias2 = bv
//  mat 3: KBt = Wk @ Wb           (applied to x_src)   bias3 = Wk@bb + bk
//  mat 4: VBt = Wv @ Wb           (applied to x_src)   bias4 = Wv@bb + bv
//  mat 5: Ot  = Wo                (applied to mean msg) bias5 = bo
// Composing Wb into K/V weights removes the per-edge x_j materialization.
// ---------------------------------------------------------------------------
__global__ __launch_bounds__(128) void prep_weights(RelW r0, RelW r1, RelW r2,
                                                    float* __restrict__ wbuf) {
  RelW R = (blockIdx.z == 0) ? r0 : (blockIdx.z == 1 ? r1 : r2);
  const int o = blockIdx.x;   // output feature 0..127
  const int m = blockIdx.y;   // mat 0..5
  const int k = threadIdx.x;  // input feature 0..127
  const float scale = 0.17677669529663687f;  // 1/sqrt(32), folded into Q
  float val;
  if (m == 0)      val = R.Win[o*128 + k] * scale;
  else if (m == 1) val = R.Win[(128+o)*128 + k];
  else if (m == 2) val = R.Win[(256+o)*128 + k];
  else if (m == 5) val = R.Wo[o*128 + k];
  else {
    const float* wr = R.Win + (m == 3 ? (128+o)*128 : (256+o)*128);
    float acc = 0.f;
    for (int i = 0; i < 128; ++i) acc += wr[i] * R.Wb[i*128 + k];
    val = acc;
  }
  float* base = wbuf + (size_t)blockIdx.z * WSTRIDE;
  base[m*16384 + k*128 + o] = val;   // transposed store [k][o]
  if (k == 0) {
    float bv;
    if (m == 0)      bv = R.bin[o] * scale;
    else if (m == 1) bv = R.bin[128+o];
    else if (m == 2) bv = R.bin[256+o];
    else if (m == 5) bv = R.bo[o];
    else {
      const float* wr = R.Win + (m == 3 ? (128+o)*128 : (256+o)*128);
      float acc = (m == 3) ? R.bin[128+o] : R.bin[256+o];
      for (int i = 0; i < 128; ++i) acc += wr[i] * R.bb[i];
      bv = acc;
    }
    base[6*16384 + m*128 + o] = bv;
  }
}

// ---------------------------------------------------------------------------
// Projection GEMM: out[mat][m][o] = X[m][:] . Wt[mat][:][o] + bias[mat][o]
// X [M,128] row-major; Wt = consecutive [128][128] transposed mats; outputs
// are consecutive [M,128] buffers (mat stride = outMatStride floats).
// Tile: 64 rows x 64 cols per block of 256 threads, 4x4 register micro-tile.
// ---------------------------------------------------------------------------
__global__ __launch_bounds__(256) void gemm_proj(
    const float* __restrict__ X, const float* __restrict__ Wt,
    const float* __restrict__ bias, float* __restrict__ out,
    long outMatStride, int M)
{
  __shared__ float xs[32][68];   // [k][row]  (stride 68: b128-aligned, 2-way banks)
  __shared__ float wsm[32][68];  // [k][col]
  const int m0 = blockIdx.x * 64;
  const int c0 = blockIdx.y * 64;        // global col over concatenated mats
  const int mat = c0 >> 7;
  const int oc0 = c0 & 127;
  const int t = threadIdx.x;
  const int tx = t & 15, ty = t >> 4;
  const int lr = t >> 3;          // 0..31 (x row)
  const int lk = (t & 7) * 4;     // k offset
  const int wk = t >> 3;          // 0..31 (w k-row)
  const int wc = (t & 7) * 8;     // col offset
  float acc[4][4] = {};
  for (int kc = 0; kc < 128; kc += 32) {
    float4 x0 = *(const float4*)&X[(long)(m0 + lr) * 128 + kc + lk];
    float4 x1 = *(const float4*)&X[(long)(m0 + lr + 32) * 128 + kc + lk];
    const float* wr = &Wt[(long)mat * 16384 + (long)(kc + wk) * 128 + oc0 + wc];
    float4 w0 = *(const float4*)&wr[0];
    float4 w1 = *(const float4*)&wr[4];
    __syncthreads();
    xs[lk+0][lr] = x0.x; xs[lk+1][lr] = x0.y; xs[lk+2][lr] = x0.z; xs[lk+3][lr] = x0.w;
    xs[lk+0][lr+32] = x1.x; xs[lk+1][lr+32] = x1.y; xs[lk+2][lr+32] = x1.z; xs[lk+3][lr+32] = x1.w;
    *(float4*)&wsm[wk][wc]     = w0;
    *(float4*)&wsm[wk][wc + 4] = w1;
    __syncthreads();
    #pragma unroll
    for (int kk = 0; kk < 32; ++kk) {
      float4 xv = *(const float4*)&xs[kk][ty * 4];
      float4 wv = *(const float4*)&wsm[kk][tx * 4];
      acc[0][0] += xv.x*wv.x; acc[0][1] += xv.x*wv.y; acc[0][2] += xv.x*wv.z; acc[0][3] += xv.x*wv.w;
      acc[1][0] += xv.y*wv.x; acc[1][1] += xv.y*wv.y; acc[1][2] += xv.y*wv.z; acc[1][3] += xv.y*wv.w;
      acc[2][0] += xv.z*wv.x; acc[2][1] += xv.z*wv.y; acc[2][2] += xv.z*wv.z; acc[2][3] += xv.z*wv.w;
      acc[3][0] += xv.w*wv.x; acc[3][1] += xv.w*wv.y; acc[3][2] += xv.w*wv.z; acc[3][3] += xv.w*wv.w;
    }
  }
  float b[4];
  #pragma unroll
  for (int j = 0; j < 4; ++j) b[j] = bias[c0 + tx * 4 + j];
  #pragma unroll
  for (int i = 0; i < 4; ++i) {
    const int m = m0 + ty * 4 + i;
    float4 v = make_float4(acc[i][0] + b[0], acc[i][1] + b[1],
                           acc[i][2] + b[2], acc[i][3] + b[3]);
    *(float4*)&out[(long)mat * outMatStride + (long)m * 128 + oc0 + tx * 4] = v;
  }
}

// ---------------------------------------------------------------------------
// Finalize: out = alpha * [ cnt>0 ? (accum/cnt) @ Wo.T + bo : 0 ]  (+= if addTo)
// Same tile structure as gemm_proj; row-scales X by 1/cnt on LDS load.
// ---------------------------------------------------------------------------
__global__ __launch_bounds__(256) void gemm_final(
    const float* __restrict__ Xacc, const float* __restrict__ cntb,
    const float* __restrict__ Wt, const float* __restrict__ bias,
    float* __restrict__ out, float alpha, int addTo, int M)
{
  __shared__ float xs[32][68];
  __shared__ float wsm[32][68];
  const int m0 = blockIdx.x * 64;
  const int oc0 = blockIdx.y * 64;
  const int t = threadIdx.x;
  const int tx = t & 15, ty = t >> 4;
  const int lr = t >> 3;
  const int lk = (t & 7) * 4;
  const int wk = t >> 3;
  const int wc = (t & 7) * 8;
  const float c0v = cntb[(m0 + lr) >> 3];
  const float c1v = cntb[(m0 + lr + 32) >> 3];
  const float inv0 = c0v > 0.f ? 1.f / c0v : 0.f;
  const float inv1 = c1v > 0.f ? 1.f / c1v : 0.f;
  float acc[4][4] = {};
  for (int kc = 0; kc < 128; kc += 32) {
    float4 x0 = *(const float4*)&Xacc[(long)(m0 + lr) * 128 + kc + lk];
    float4 x1 = *(const float4*)&Xacc[(long)(m0 + lr + 32) * 128 + kc + lk];
    const float* wr = &Wt[(long)(kc + wk) * 128 + oc0 + wc];
    float4 w0 = *(const float4*)&wr[0];
    float4 w1 = *(const float4*)&wr[4];
    __syncthreads();
    xs[lk+0][lr] = x0.x*inv0; xs[lk+1][lr] = x0.y*inv0; xs[lk+2][lr] = x0.z*inv0; xs[lk+3][lr] = x0.w*inv0;
    xs[lk+0][lr+32] = x1.x*inv1; xs[lk+1][lr+32] = x1.y*inv1; xs[lk+2][lr+32] = x1.z*inv1; xs[lk+3][lr+32] = x1.w*inv1;
    *(float4*)&wsm[wk][wc]     = w0;
    *(float4*)&wsm[wk][wc + 4] = w1;
    __syncthreads();
    #pragma unroll
    for (int kk = 0; kk < 32; ++kk) {
      float4 xv = *(const float4*)&xs[kk][ty * 4];
      float4 wv = *(const float4*)&wsm[kk][tx * 4];
      acc[0][0] += xv.x*wv.x; acc[0][1] += xv.x*wv.y; acc[0][2] += xv.x*wv.z; acc[0][3] += xv.x*wv.w;
      acc[1][0] += xv.y*wv.x; acc[1][1] += xv.y*wv.y; acc[1][2] += xv.y*wv.z; acc[1][3] += xv.y*wv.w;
      acc[2][0] += xv.z*wv.x; acc[2][1] += xv.z*wv.y; acc[2][2] += xv.z*wv.z; acc[2][3] += xv.z*wv.w;
      acc[3][0] += xv.w*wv.x; acc[3][1] += xv.w*wv.y; acc[3][2] += xv.w*wv.z; acc[3][3] += xv.w*wv.w;
    }
  }
  float b[4];
  #pragma unroll
  for (int j = 0; j < 4; ++j) b[j] = bias[oc0 + tx * 4 + j];
  #pragma unroll
  for (int i = 0; i < 4; ++i) {
    const int m = m0 + ty * 4 + i;
    const bool has = cntb[m >> 3] > 0.f;
    float4 v;
    v.x = has ? (acc[i][0] + b[0]) * alpha : 0.f;
    v.y = has ? (acc[i][1] + b[1]) * alpha : 0.f;
    v.z = has ? (acc[i][2] + b[2]) * alpha : 0.f;
    v.w = has ? (acc[i][3] + b[3]) * alpha : 0.f;
    float* op = &out[(long)m * 128 + oc0 + tx * 4];
    if (addTo) { float4 o = *(float4*)op; v.x += o.x; v.y += o.y; v.z += o.z; v.w += o.w; }
    *(float4*)op = v;
  }
}

// ---------------------------------------------------------------------------
// Per-edge attention. One block per edge. Gathers precomputed per-node
// fragments: Q/Ki/Vi by dst, Kj/Vj by src; K/V = concat(i-part, j-part) on the
// sequence axis (rows 0..7 dst, 8..15 src) per the reference concat.
// Softmax over 16 keys per (head, query-token); message atomically added into
// per-dst accumulator (Wo applied later, after segment-mean).
// ---------------------------------------------------------------------------
__global__ __launch_bounds__(256) void edge_attn(
    const float* __restrict__ Q, const float* __restrict__ Ki,
    const float* __restrict__ Vi, const float* __restrict__ Kj,
    const float* __restrict__ Vj, const int* __restrict__ ei,
    float* __restrict__ accum, float* __restrict__ cntb, int E)
{
  __shared__ float sQ[8][132];    // +4 pad: b128-aligned, 2-way banks max
  __shared__ float sK[16][132];
  __shared__ float sV[16][132];
  __shared__ float sAtt[4][8][16];
  const int e = blockIdx.x;
  const int s = ei[e];          // src row
  const int d = ei[E + e];      // dst row
  const int t = threadIdx.x;

  // stage 20KB of per-node fragments (coalesced float4)
  {
    const int row = t >> 5;            // 0..7
    const int col = (t & 31) * 4;
    const long db = (long)d * NODE_F;
    const long sb = (long)s * NODE_F;
    *(float4*)&sQ[row][col]     = *(const float4*)&Q[db + t * 4];
    *(float4*)&sK[row][col]     = *(const float4*)&Ki[db + t * 4];
    *(float4*)&sK[8 + row][col] = *(const float4*)&Kj[sb + t * 4];
    *(float4*)&sV[row][col]     = *(const float4*)&Vi[db + t * 4];
    *(float4*)&sV[8 + row][col] = *(const float4*)&Vj[sb + t * 4];
  }
  __syncthreads();

  // scores: 512 = H*S*2S; thread does 2 consecutive k for one (h,q) so the
  // Q fragment stays in registers (scale already folded into Q weights)
  {
    const int si = t * 2;
    const int k0 = si & 15, q = (si >> 4) & 7, h = si >> 7;
    const float* qp = &sQ[q][h * 32];
    float4 qv[8];
    #pragma unroll
    for (int j = 0; j < 8; ++j) qv[j] = *(const float4*)&qp[j * 4];
    #pragma unroll
    for (int kk = 0; kk < 2; ++kk) {
      const float* kp = &sK[k0 + kk][h * 32];
      float acc = 0.f;
      #pragma unroll
      for (int j = 0; j < 8; ++j) {
        float4 b = *(const float4*)&kp[j * 4];
        acc += qv[j].x*b.x + qv[j].y*b.y + qv[j].z*b.z + qv[j].w*b.w;
      }
      sAtt[h][q][k0 + kk] = acc;
    }
  }
  __syncthreads();

  // softmax over k (16) for each of the 32 (h,q) rows
  if (t < 32) {
    const int h = t >> 3, q = t & 7;
    float* row = sAtt[h][q];
    float mx = row[0];
    #pragma unroll
    for (int k = 1; k < 16; ++k) mx = fmaxf(mx, row[k]);
    float ex[16], sum = 0.f;
    #pragma unroll
    for (int k = 0; k < 16; ++k) { ex[k] = __expf(row[k] - mx); sum += ex[k]; }
    const float inv = 1.f / sum;
    #pragma unroll
    for (int k = 0; k < 16; ++k) row[k] = ex[k] * inv;
  }
  __syncthreads();

  // O = att @ V, atomically accumulated into accum[dst]. Thread owns one
  // feature column f across 4 query tokens -> sV[k][f] loaded once per k.
  {
    const int f = t & 127;
    const int h = f >> 5;
    const int qb = t >> 7;               // q = qb + 2*oi
    float oacc[4] = {0.f, 0.f, 0.f, 0.f};
    #pragma unroll
    for (int k = 0; k < 16; ++k) {
      const float v = sV[k][f];
      #pragma unroll
      for (int oi = 0; oi < 4; ++oi) oacc[oi] += sAtt[h][qb + 2*oi][k] * v;
    }
    const long base = (long)d * NODE_F;
    #pragma unroll
    for (int oi = 0; oi < 4; ++oi)
      atomicAdd(&accum[base + (qb + 2*oi) * 128 + f], oacc[oi]);
  }
  if (t == 0) atomicAdd(&cntb[d], 1.0f);
}

// ---------------------------------------------------------------------------
extern "C" void kernel_launch(void* const* d_in, const int* in_sizes, int n_in,
                              void* d_out, int out_size, void* d_ws, size_t ws_size,
                              hipStream_t stream)
{
  const float* x_a = (const float*)d_in[0];
  const float* x_b = (const float*)d_in[1];
  const int* ei[3] = { (const int*)d_in[2], (const int*)d_in[3], (const int*)d_in[4] };
  RelW rw[3];
  for (int r = 0; r < 3; ++r) {
    const int base = 5 + r * 6;
    rw[r].Wb  = (const float*)d_in[base + 0];
    rw[r].bb  = (const float*)d_in[base + 1];
    rw[r].Win = (const float*)d_in[base + 2];
    rw[r].bin = (const float*)d_in[base + 3];
    rw[r].Wo  = (const float*)d_in[base + 4];
    rw[r].bo  = (const float*)d_in[base + 5];
  }
  const int N = in_sizes[0] / NODE_F;      // 20000
  const int E = in_sizes[2] / 2;           // 100000
  const int M = N * S_TOK;                 // 160000 rows (divisible by 64)
  const size_t NF = (size_t)N * NODE_F;

  // workspace: 5 proj buffers + accum + cnt + prepped weights  (~493 MB)
  float* ws   = (float*)d_ws;
  float* Qb   = ws;             // [N,8,128]  (Q of dst, scale folded)
  float* Kib  = Qb  + NF;       // K from dst features
  float* Vib  = Kib + NF;
  float* Kjb  = Vib + NF;       // K from src features (Wb composed)
  float* Vjb  = Kjb + NF;
  float* accum= Vjb + NF;       // per-dst message sum
  float* cntb = accum + NF;     // per-dst edge count (float)
  float* wbuf = cntb + N;       // 3 * WSTRIDE

  float* outA = (float*)d_out;  // [N,8,128] : (r2 + r3) * 0.5
  float* outB = outA + NF;      // [N,8,128] : r1

  prep_weights<<<dim3(128, 6, 3), 128, 0, stream>>>(rw[0], rw[1], rw[2], wbuf);

  const float* srcX[3] = { x_a, x_b, x_a };
  const float* dstX[3] = { x_b, x_a, x_a };
  float* outP[3]       = { outB, outA, outA };
  const float alpha[3] = { 1.0f, 0.5f, 0.5f };
  const int addTo[3]   = { 0, 0, 1 };

  for (int r = 0; r < 3; ++r) {
    hipMemsetAsync(accum, 0, NF * sizeof(float), stream);
    hipMemsetAsync(cntb, 0, N * sizeof(float), stream);
    const float* wb = wbuf + (size_t)r * WSTRIDE;
    // dst-side fused QKV (mats 0..2 -> Qb,Kib,Vib)
    gemm_proj<<<dim3(M / 64, 6), 256, 0, stream>>>(dstX[r], wb, wb + 6*16384, Qb, (long)NF, M);
    // src-side fused K/V with Wb composed (mats 3..4 -> Kjb,Vjb)
    gemm_proj<<<dim3(M / 64, 4), 256, 0, stream>>>(srcX[r], wb + 3*16384, wb + 6*16384 + 3*128, Kjb, (long)NF, M);
    edge_attn<<<dim3(E), 256, 0, stream>>>(Qb, Kib, Vib, Kjb, Vjb, ei[r], accum, cntb, E);
    gemm_final<<<dim3(M / 64, 2), 256, 0, stream>>>(accum, cntb, wb + 5*16384, wb + 6*16384 + 5*128,
                                                    outP[r], alpha[r], addTo[r], M);
  }
}

// Round 2
// 1644.963 us; speedup vs baseline: 1.6627x; 1.6627x over previous
//
#include <hip/hip_runtime.h>

// Shapes fixed by the reference: H=4, D=128, S=8, dh=32.
#define NODE_F 1024                     // 8*128 elems per node

typedef short bf16x8 __attribute__((ext_vector_type(8)));
typedef float f32x4  __attribute__((ext_vector_type(4)));

__device__ inline ushort f2bf(float f) {
  union { float f; unsigned u; } v; v.f = f;
  unsigned r = v.u + 0x7FFFu + ((v.u >> 16) & 1u);   // RNE
  return (ushort)(r >> 16);
}
__device__ inline float bf2f(ushort u) {
  union { unsigned u; float f; } v; v.u = ((unsigned)u) << 16;
  return v.f;
}

struct RelW { const float *Win, *bin, *Wb, *bb, *Wo, *bo; };

// ---------------------------------------------------------------------------
// Weight prep. Mats 0..4 (Q,Ki,Vi,KB,VB; Wb composed into KB/VB; 1/sqrt(dh)
// folded into Q) are stored as bf16 in EXACT mfma_16x16x32 A-operand fragment
// order so gemm_mfma loads them with zero shuffling:
//   A'[o][k]: lane = quad*16 + (o&15), k = ks*32 + quad*8 + j
//   index = (((mat*4+ks)*8 + (o>>4))*64 + lane)*8 + j
// Mat 5 (Wo) stays fp32 transposed [k][o] for the fp32 finalize GEMM.
// ---------------------------------------------------------------------------
__global__ __launch_bounds__(128) void prep_weights(RelW r0, RelW r1, RelW r2,
    ushort* __restrict__ Wfrag, float* __restrict__ WoT,
    float* __restrict__ biasQKV, float* __restrict__ biasO)
{
  const int rel = blockIdx.z;
  RelW R = (rel == 0) ? r0 : (rel == 1 ? r1 : r2);
  const int o = blockIdx.x, m = blockIdx.y, k = threadIdx.x;
  const float scale = 0.17677669529663687f;   // 1/sqrt(32)
  float val;
  if (m == 0)      val = R.Win[o*128 + k] * scale;
  else if (m == 1) val = R.Win[(128+o)*128 + k];
  else if (m == 2) val = R.Win[(256+o)*128 + k];
  else if (m == 5) val = R.Wo[o*128 + k];
  else {
    const float* wr = R.Win + (m == 3 ? (128+o)*128 : (256+o)*128);
    float acc = 0.f;
    for (int i = 0; i < 128; ++i) acc += wr[i] * R.Wb[i*128 + k];
    val = acc;
  }
  if (m < 5) {
    const int ks = k >> 5, quad = (k >> 3) & 3, j = k & 7;
    const int ot = o >> 4, lane = quad * 16 + (o & 15);
    Wfrag[(size_t)rel*5*16384 + ((((m*4 + ks)*8 + ot)*64 + lane)*8 + j)] = f2bf(val);
  } else {
    WoT[(size_t)rel*16384 + k*128 + o] = val;
  }
  if (k == 0) {
    float bv;
    if (m == 0)      bv = R.bin[o] * scale;
    else if (m == 1) bv = R.bin[128+o];
    else if (m == 2) bv = R.bin[256+o];
    else if (m == 5) bv = R.bo[o];
    else {
      const float* wr = R.Win + (m == 3 ? (128+o)*128 : (256+o)*128);
      float acc = (m == 3) ? R.bin[128+o] : R.bin[256+o];
      for (int i = 0; i < 128; ++i) acc += wr[i] * R.bb[i];
      bv = acc;
    }
    if (m < 5) biasQKV[rel*640 + m*128 + o] = bv;
    else       biasO[rel*128 + o] = bv;
  }
}

// fp32 -> bf16 copies of x_a / x_b
__global__ __launch_bounds__(256) void conv_bf16(const float* __restrict__ xa,
    const float* __restrict__ xb, ushort* __restrict__ oa, ushort* __restrict__ ob)
{
  const float* x = blockIdx.y ? xb : xa;
  ushort* o = blockIdx.y ? ob : oa;
  const long i = ((long)blockIdx.x * 256 + threadIdx.x) * 4;
  float4 v = *(const float4*)&x[i];
  ushort4 r; r.x = f2bf(v.x); r.y = f2bf(v.y); r.z = f2bf(v.z); r.w = f2bf(v.w);
  *(ushort4*)&o[i] = r;
}

// --------------------------- CSR build (per relation) -----------------------
__global__ __launch_bounds__(256) void hist_edges(
    const int* __restrict__ e1, const int* __restrict__ e2, const int* __restrict__ e3,
    int* __restrict__ counts, int E, int N)
{
  const int r = blockIdx.y;
  const int* ei = (r == 0) ? e1 : (r == 1) ? e2 : e3;
  const int e = blockIdx.x * 256 + threadIdx.x;
  if (e < E) atomicAdd(&counts[(size_t)r * N + ei[E + e]], 1);
}

__global__ __launch_bounds__(1024) void scan_offsets(
    const int* __restrict__ counts, int* __restrict__ off,
    int* __restrict__ fill, int N)
{
  const int r = blockIdx.x;
  const int* cnt = counts + (size_t)r * N;
  int* offr  = off  + (size_t)r * (N + 1);
  int* fillr = fill + (size_t)r * N;
  __shared__ int buf[1024];
  __shared__ int carry;
  const int t = threadIdx.x;
  if (t == 0) carry = 0;
  __syncthreads();
  for (int base = 0; base < N; base += 1024) {
    const int idx = base + t;
    int v = (idx < N) ? cnt[idx] : 0;
    buf[t] = v;
    __syncthreads();
    for (int s = 1; s < 1024; s <<= 1) {
      int add = (t >= s) ? buf[t - s] : 0;
      __syncthreads();
      buf[t] += add;
      __syncthreads();
    }
    const int incl = buf[t];
    const int c = carry;
    if (idx < N) { offr[idx] = c + incl - v; fillr[idx] = c + incl - v; }
    __syncthreads();
    if (t == 1023) carry = c + incl;
    __syncthreads();
  }
  if (t == 0) offr[N] = carry;
}

__global__ __launch_bounds__(256) void scatter_edges(
    const int* __restrict__ e1, const int* __restrict__ e2, const int* __restrict__ e3,
    int* __restrict__ fill, int* __restrict__ esrc, int E, int N)
{
  const int r = blockIdx.y;
  const int* ei = (r == 0) ? e1 : (r == 1) ? e2 : e3;
  const int e = blockIdx.x * 256 + threadIdx.x;
  if (e < E) {
    const int d = ei[E + e], s = ei[e];
    const int pos = atomicAdd(&fill[(size_t)r * N + d], 1);
    esrc[(size_t)r * E + pos] = s;
  }
}

// ---------------------------------------------------------------------------
// MFMA projection GEMM. Block = 128 rows x 128 cols (= one mat; mat =
// blockIdx.y), 4 waves in a 2x2 wave grid, each wave 4x4 tiles of 16x16.
// Operand trick: A = pre-swizzled W fragments (M-index = output feature o),
// B = X rows (N-index = node row m)  =>  D[o][m] with D col(lane&15) = m,
// row(quad*4+reg) = o, so each lane packs 4 consecutive o as one 8B bf16x4
// store. No LDS anywhere.
// ---------------------------------------------------------------------------
__global__ __launch_bounds__(256) void gemm_mfma(
    const ushort* __restrict__ X16, const ushort* __restrict__ Wfrag,
    const float* __restrict__ biasQKV, ushort* __restrict__ Out, long matStride)
{
  const int mat = blockIdx.y;
  const long m0 = (long)blockIdx.x * 128;
  const int t = threadIdx.x, wave = t >> 6, lane = t & 63;
  const int wm = (wave & 1) * 64, wo = (wave >> 1) * 64;
  const int lrow = lane & 15, quad = lane >> 4;
  f32x4 acc[4][4];
  #pragma unroll
  for (int i = 0; i < 4; ++i)
    #pragma unroll
    for (int j = 0; j < 4; ++j) acc[i][j] = (f32x4){0.f, 0.f, 0.f, 0.f};
  #pragma unroll
  for (int ks = 0; ks < 4; ++ks) {
    bf16x8 af[4], bx[4];
    #pragma unroll
    for (int ot = 0; ot < 4; ++ot)
      af[ot] = *(const bf16x8*)&Wfrag[((((mat*4 + ks)*8) + (wo >> 4) + ot)*64 + lane)*8];
    #pragma unroll
    for (int mt = 0; mt < 4; ++mt)
      bx[mt] = *(const bf16x8*)&X16[(m0 + wm + mt*16 + lrow)*128 + ks*32 + quad*8];
    #pragma unroll
    for (int mt = 0; mt < 4; ++mt)
      #pragma unroll
      for (int ot = 0; ot < 4; ++ot)
        acc[mt][ot] = __builtin_amdgcn_mfma_f32_16x16x32_bf16(af[ot], bx[mt], acc[mt][ot], 0, 0, 0);
  }
  #pragma unroll
  for (int ot = 0; ot < 4; ++ot) {
    const int ocol = wo + ot*16 + quad*4;
    const float4 b4 = *(const float4*)&biasQKV[mat*128 + ocol];
    #pragma unroll
    for (int mt = 0; mt < 4; ++mt) {
      const long m = m0 + wm + mt*16 + lrow;
      ushort4 r;
      r.x = f2bf(acc[mt][ot][0] + b4.x);
      r.y = f2bf(acc[mt][ot][1] + b4.y);
      r.z = f2bf(acc[mt][ot][2] + b4.z);
      r.w = f2bf(acc[mt][ot][3] + b4.w);
      *(ushort4*)&Out[(size_t)mat * matStride + m*128 + ocol] = r;
    }
  }
}

// ---------------------------------------------------------------------------
// Dst-centric attention: one block per dst node, iterate its CSR bucket.
// Dst-side Q/Ki/Vi staged once (bf16->fp32 in LDS); dst-dst scores cached
// (identical for every edge). Per edge: load src K/V rows, src-half scores,
// softmax over 16 keys, AV accumulated in registers; single store per node.
// ---------------------------------------------------------------------------
__global__ __launch_bounds__(256) void node_attn(
    const ushort* __restrict__ Q, const ushort* __restrict__ Ki,
    const ushort* __restrict__ Vi, const ushort* __restrict__ Kj,
    const ushort* __restrict__ Vj, const int* __restrict__ off,
    const int* __restrict__ esrc, float* __restrict__ accum)
{
  __shared__ float sQ[8][132];
  __shared__ float sK[16][132];
  __shared__ float sV[16][132];
  __shared__ float sAttD[4][8][8];   // dst-dst raw scores (edge-invariant)
  __shared__ float sAtt[4][8][16];   // per-edge: src scores then probs
  const int n = blockIdx.x;
  const int t = threadIdx.x;
  const int e0 = off[n], deg = off[n + 1] - e0;
  if (deg == 0) return;   // gemm_final multiplies accum by inv=0 -> safe

  {
    const int row = t >> 5, col = (t & 31) * 4;
    const long base = (long)n * NODE_F + t * 4;
    ushort4 q4 = *(const ushort4*)&Q[base];
    ushort4 k4 = *(const ushort4*)&Ki[base];
    ushort4 v4 = *(const ushort4*)&Vi[base];
    sQ[row][col]   = bf2f(q4.x); sQ[row][col+1] = bf2f(q4.y);
    sQ[row][col+2] = bf2f(q4.z); sQ[row][col+3] = bf2f(q4.w);
    sK[row][col]   = bf2f(k4.x); sK[row][col+1] = bf2f(k4.y);
    sK[row][col+2] = bf2f(k4.z); sK[row][col+3] = bf2f(k4.w);
    sV[row][col]   = bf2f(v4.x); sV[row][col+1] = bf2f(v4.y);
    sV[row][col+2] = bf2f(v4.z); sV[row][col+3] = bf2f(v4.w);
  }
  __syncthreads();

  // fixed per-thread score slot (h,q,k) and Q row cached in registers
  const int sk = t & 7, sq = (t >> 3) & 7, sh = t >> 6;
  float4 qv[8];
  #pragma unroll
  for (int j = 0; j < 8; ++j) qv[j] = *(const float4*)&sQ[sq][sh*32 + j*4];
  {
    float a = 0.f;
    const float* kp = &sK[sk][sh*32];
    #pragma unroll
    for (int j = 0; j < 8; ++j) {
      float4 b = *(const float4*)&kp[j*4];
      a += qv[j].x*b.x + qv[j].y*b.y + qv[j].z*b.z + qv[j].w*b.w;
    }
    sAttD[sh][sq][sk] = a;
  }

  const int f = t & 127, avh = f >> 5, qb = t >> 7;
  float oacc[4] = {0.f, 0.f, 0.f, 0.f};

  for (int i = 0; i < deg; ++i) {
    const int s = esrc[e0 + i];
    const long sb = (long)s * NODE_F + t * 4;
    ushort4 k4 = *(const ushort4*)&Kj[sb];
    ushort4 v4 = *(const ushort4*)&Vj[sb];
    __syncthreads();            // prev AV reads of sK/sV/sAtt done (covers sAttD on i=0)
    {
      const int row = 8 + (t >> 5), col = (t & 31) * 4;
      sK[row][col]   = bf2f(k4.x); sK[row][col+1] = bf2f(k4.y);
      sK[row][col+2] = bf2f(k4.z); sK[row][col+3] = bf2f(k4.w);
      sV[row][col]   = bf2f(v4.x); sV[row][col+1] = bf2f(v4.y);
      sV[row][col+2] = bf2f(v4.z); sV[row][col+3] = bf2f(v4.w);
    }
    __syncthreads();
    {   // src-half scores
      float a = 0.f;
      const float* kp = &sK[8 + sk][sh*32];
      #pragma unroll
      for (int j = 0; j < 8; ++j) {
        float4 b = *(const float4*)&kp[j*4];
        a += qv[j].x*b.x + qv[j].y*b.y + qv[j].z*b.z + qv[j].w*b.w;
      }
      sAtt[sh][sq][8 + sk] = a;
    }
    __syncthreads();
    if (t < 32) {               // softmax over 16 keys per (h,q)
      const int h = t >> 3, q = t & 7;
      float r[16];
      #pragma unroll
      for (int k = 0; k < 8; ++k) r[k] = sAttD[h][q][k];
      #pragma unroll
      for (int k = 0; k < 8; ++k) r[8+k] = sAtt[h][q][8+k];
      float mx = r[0];
      #pragma unroll
      for (int k = 1; k < 16; ++k) mx = fmaxf(mx, r[k]);
      float sum = 0.f;
      #pragma unroll
      for (int k = 0; k < 16; ++k) { r[k] = __expf(r[k] - mx); sum += r[k]; }
      const float inv = 1.f / sum;
      #pragma unroll
      for (int k = 0; k < 16; ++k) sAtt[h][q][k] = r[k] * inv;
    }
    __syncthreads();
    #pragma unroll
    for (int k = 0; k < 16; ++k) {   // AV: thread owns col f, 4 q's
      const float v = sV[k][f];
      #pragma unroll
      for (int oi = 0; oi < 4; ++oi) oacc[oi] += sAtt[avh][qb + 2*oi][k] * v;
    }
  }
  const long ob = (long)n * NODE_F;
  #pragma unroll
  for (int oi = 0; oi < 4; ++oi)
    accum[ob + (qb + 2*oi)*128 + f] = oacc[oi];
}

// ---------------------------------------------------------------------------
// Finalize (fp32): out = alpha * [cnt>0 ? (accum/cnt) @ WoT + bo : 0] (+= opt)
// ---------------------------------------------------------------------------
__global__ __launch_bounds__(256) void gemm_final(
    const float* __restrict__ Xacc, const int* __restrict__ cnt,
    const float* __restrict__ Wt, const float* __restrict__ bias,
    float* __restrict__ out, float alpha, int addTo, int M)
{
  __shared__ float xs[32][68];
  __shared__ float wsm[32][68];
  const int m0 = blockIdx.x * 64;
  const int oc0 = blockIdx.y * 64;
  const int t = threadIdx.x;
  const int tx = t & 15, ty = t >> 4;
  const int lr = t >> 3;
  const int lk = (t & 7) * 4;
  const int wk = t >> 3;
  const int wc = (t & 7) * 8;
  const int c0i = cnt[(m0 + lr) >> 3];
  const int c1i = cnt[(m0 + lr + 32) >> 3];
  const float inv0 = c0i > 0 ? 1.f / (float)c0i : 0.f;
  const float inv1 = c1i > 0 ? 1.f / (float)c1i : 0.f;
  float acc[4][4] = {};
  for (int kc = 0; kc < 128; kc += 32) {
    float4 x0 = *(const float4*)&Xacc[(long)(m0 + lr) * 128 + kc + lk];
    float4 x1 = *(const float4*)&Xacc[(long)(m0 + lr + 32) * 128 + kc + lk];
    const float* wr = &Wt[(long)(kc + wk) * 128 + oc0 + wc];
    float4 w0 = *(const float4*)&wr[0];
    float4 w1 = *(const float4*)&wr[4];
    __syncthreads();
    xs[lk+0][lr] = x0.x*inv0; xs[lk+1][lr] = x0.y*inv0; xs[lk+2][lr] = x0.z*inv0; xs[lk+3][lr] = x0.w*inv0;
    xs[lk+0][lr+32] = x1.x*inv1; xs[lk+1][lr+32] = x1.y*inv1; xs[lk+2][lr+32] = x1.z*inv1; xs[lk+3][lr+32] = x1.w*inv1;
    *(float4*)&wsm[wk][wc]     = w0;
    *(float4*)&wsm[wk][wc + 4] = w1;
    __syncthreads();
    #pragma unroll
    for (int kk = 0; kk < 32; ++kk) {
      float4 xv = *(const float4*)&xs[kk][ty * 4];
      float4 wv = *(const float4*)&wsm[kk][tx * 4];
      acc[0][0] += xv.x*wv.x; acc[0][1] += xv.x*wv.y; acc[0][2] += xv.x*wv.z; acc[0][3] += xv.x*wv.w;
      acc[1][0] += xv.y*wv.x; acc[1][1] += xv.y*wv.y; acc[1][2] += xv.y*wv.z; acc[1][3] += xv.y*wv.w;
      acc[2][0] += xv.z*wv.x; acc[2][1] += xv.z*wv.y; acc[2][2] += xv.z*wv.z; acc[2][3] += xv.z*wv.w;
      acc[3][0] += xv.w*wv.x; acc[3][1] += xv.w*wv.y; acc[3][2] += xv.w*wv.z; acc[3][3] += xv.w*wv.w;
    }
  }
  float b[4];
  #pragma unroll
  for (int j = 0; j < 4; ++j) b[j] = bias[oc0 + tx * 4 + j];
  #pragma unroll
  for (int i = 0; i < 4; ++i) {
    const int m = m0 + ty * 4 + i;
    const bool has = cnt[m >> 3] > 0;
    float4 v;
    v.x = has ? (acc[i][0] + b[0]) * alpha : 0.f;
    v.y = has ? (acc[i][1] + b[1]) * alpha : 0.f;
    v.z = has ? (acc[i][2] + b[2]) * alpha : 0.f;
    v.w = has ? (acc[i][3] + b[3]) * alpha : 0.f;
    float* op = &out[(long)m * 128 + oc0 + tx * 4];
    if (addTo) { float4 o = *(float4*)op; v.x += o.x; v.y += o.y; v.z += o.z; v.w += o.w; }
    *(float4*)op = v;
  }
}

// ---------------------------------------------------------------------------
extern "C" void kernel_launch(void* const* d_in, const int* in_sizes, int n_in,
                              void* d_out, int out_size, void* d_ws, size_t ws_size,
                              hipStream_t stream)
{
  const float* x_a = (const float*)d_in[0];
  const float* x_b = (const float*)d_in[1];
  const int* ei[3] = { (const int*)d_in[2], (const int*)d_in[3], (const int*)d_in[4] };
  RelW rw[3];
  for (int r = 0; r < 3; ++r) {
    const int base = 5 + r * 6;
    rw[r].Wb  = (const float*)d_in[base + 0];
    rw[r].bb  = (const float*)d_in[base + 1];
    rw[r].Win = (const float*)d_in[base + 2];
    rw[r].bin = (const float*)d_in[base + 3];
    rw[r].Wo  = (const float*)d_in[base + 4];
    rw[r].bo  = (const float*)d_in[base + 5];
  }
  const int N = in_sizes[0] / NODE_F;   // 20000
  const int E = in_sizes[2] / 2;        // 100000
  const int M = N * 8;                  // 160000 token rows (M%128==0)
  const size_t NF = (size_t)N * NODE_F;

  // ---- workspace carve-up (~370 MB) ----
  ushort* Qb    = (ushort*)d_ws;        // dst Q  (scale folded)   [NF] bf16
  ushort* Kib   = Qb  + NF;             // dst K                   (Q,Ki,Vi contiguous)
  ushort* Vib   = Kib + NF;
  ushort* Kjb   = Vib + NF;             // src K (Wb composed)     (Kj,Vj contiguous)
  ushort* Vjb   = Kjb + NF;
  ushort* xa16  = Vjb + NF;
  ushort* xb16  = xa16 + NF;
  ushort* Wfrag = xb16 + NF;            // 3 * 5*16384 bf16
  float* accum  = (float*)(Wfrag + (size_t)3*5*16384);   // [NF] fp32
  float* WoT    = accum + NF;           // 3 * 16384
  float* biasQKV= WoT + (size_t)3*16384;// 3 * 640
  float* biasO  = biasQKV + 3*640;      // 3 * 128
  int* counts   = (int*)(biasO + 3*128);// 3 * N
  int* offb     = counts + 3*N;         // 3 * (N+1)
  int* fillb    = offb + 3*(N+1);       // 3 * N
  int* esrc     = fillb + 3*N;          // 3 * E

  float* outA = (float*)d_out;          // (r2 + r3) * 0.5
  float* outB = outA + NF;              // r1

  // ---- CSR build for all relations (independent of weights) ----
  hipMemsetAsync(counts, 0, (size_t)3 * N * sizeof(int), stream);
  hist_edges<<<dim3((E + 255) / 256, 3), 256, 0, stream>>>(ei[0], ei[1], ei[2], counts, E, N);
  scan_offsets<<<3, 1024, 0, stream>>>(counts, offb, fillb, N);
  scatter_edges<<<dim3((E + 255) / 256, 3), 256, 0, stream>>>(ei[0], ei[1], ei[2], fillb, esrc, E, N);

  conv_bf16<<<dim3(N, 2), 256, 0, stream>>>(x_a, x_b, xa16, xb16);
  prep_weights<<<dim3(128, 6, 3), 128, 0, stream>>>(rw[0], rw[1], rw[2], Wfrag, WoT, biasQKV, biasO);

  const ushort* srcX[3] = { xa16, xb16, xa16 };
  const ushort* dstX[3] = { xb16, xa16, xa16 };
  float* outP[3]        = { outB, outA, outA };
  const float alpha[3]  = { 1.0f, 0.5f, 0.5f };
  const int addTo[3]    = { 0, 0, 1 };

  for (int r = 0; r < 3; ++r) {
    const ushort* wf = Wfrag + (size_t)r * 5 * 16384;
    const float* bq = biasQKV + r * 640;
    // dst-side Q/Ki/Vi (mats 0..2)
    gemm_mfma<<<dim3(M / 128, 3), 256, 0, stream>>>(dstX[r], wf, bq, Qb, (long)NF);
    // src-side Kj/Vj (mats 3..4)
    gemm_mfma<<<dim3(M / 128, 2), 256, 0, stream>>>(srcX[r], wf + (size_t)3*16384, bq + 3*128, Kjb, (long)NF);
    node_attn<<<dim3(N), 256, 0, stream>>>(Qb, Kib, Vib, Kjb, Vjb,
                                           offb + (size_t)r*(N+1), esrc + (size_t)r*E, accum);
    gemm_final<<<dim3(M / 64, 2), 256, 0, stream>>>(accum, counts + (size_t)r*N,
                                                    WoT + (size_t)r*16384, biasO + r*128,
                                                    outP[r], alpha[r], addTo[r], M);
  }
}